// Round 1
// 88.300 us; speedup vs baseline: 1.0139x; 1.0139x over previous
//
#include <hip/hip_runtime.h>
#include <hip/hip_bf16.h>

#define NG     2048
#define HW     128
#define NPIX   (HW*HW)
#define SEG    16
#define CHUNK  (NG/SEG)   // 128
#define NEARZ  0.3f
#define GEPS   1e-4f
#define LOG2E  1.4426950408889634f

// ---- sorted gaussian tables (device globals; rewritten every call) -------
__device__ float4   g_ga_s[NG];  // u, v, A, B   (conic pre-scaled by -0.5*log2e)
__device__ float4   g_gb_s[NG];  // C, opa_masked, cr, cg
__device__ float    g_cb_s[NG];
__device__ unsigned g_bb_s[NG];  // packed AABB: ymin<<24|ymax<<16|xmin<<8|xmax

__device__ __forceinline__ float sigm(float x) { return 1.0f / (1.0f + __expf(-x)); }

// dtype discriminator (inputs proven f32 in R2; kept for safety):
// rot[0][1]==0.0 exactly -> 16-bit word #1 is 0x0000 for bf16, 0x3F7F for f32.
__device__ __forceinline__ bool detect_f32(const void* rot) {
    return ((const unsigned short*)rot)[1] != 0;
}
__device__ __forceinline__ float ld(const void* p, int idx, bool f32) {
    if (f32) return ((const float*)p)[idx];
    return __bfloat162float(((const __hip_bfloat16*)p)[idx]);
}

// ---------------------------------------------------------------------------
// Kernel 1: fused preprocess + stable rank sort + AABB computation.
// 128 blocks x 256 threads (16 gaussians/block).
// NOTE (R6): do NOT merge these two kernels via cooperative grid.sync —
// measured ~100us barrier cost on gfx950 (8 non-coherent XCDs) vs ~2us
// for a plain kernel boundary.
// ---------------------------------------------------------------------------
__global__ __launch_bounds__(256)
void prep_sort_kernel(const void* __restrict__ pos,
                      const void* __restrict__ rgb,
                      const void* __restrict__ opa,
                      const void* __restrict__ quat,
                      const void* __restrict__ scale,
                      const void* __restrict__ rot,
                      const void* __restrict__ tran)
{
    __shared__ float rs[NG];
    __shared__ int   srank[16];

    int tid = threadIdx.x;
    bool f32 = detect_f32(rot);

    float R[9], T3[3];
    #pragma unroll
    for (int k = 0; k < 9; k++) R[k] = ld(rot, k, f32);
    #pragma unroll
    for (int k = 0; k < 3; k++) T3[k] = ld(tran, k, f32);

    // ---- A: sort keys for all gaussians ----
    #pragma unroll
    for (int k = 0; k < NG / 256; k++) {
        int j = tid + k * 256;
        float p0 = ld(pos, j*3+0, f32), p1 = ld(pos, j*3+1, f32), p2 = ld(pos, j*3+2, f32);
        float x = R[0]*p0 + R[1]*p1 + R[2]*p2 + T3[0];
        float y = R[3]*p0 + R[4]*p1 + R[5]*p2 + T3[1];
        float z = R[6]*p0 + R[7]*p1 + R[8]*p2 + T3[2];
        rs[j] = sqrtf(x*x + y*y + z*z);
    }
    __syncthreads();

    // ---- B: rank the block's 16 gaussians (16 lanes each) ----
    int g      = blockIdx.x * 16 + (tid >> 4);
    int lane16 = tid & 15;
    float ri = rs[g];
    int rank = 0;
    int jbase = lane16 * CHUNK;
    #pragma unroll 4
    for (int jj = 0; jj < CHUNK; jj++) {
        int j = jbase + ((jj + 2 * lane16) & (CHUNK - 1));
        float rj = rs[j];
        rank += (rj < ri) || (rj == ri && j < g);           // argsort-stable
    }
    #pragma unroll
    for (int d = 1; d < 16; d <<= 1) rank += __shfl_xor(rank, d);
    if (lane16 == 0) srank[tid >> 4] = rank;
    __syncthreads();

    // ---- C: full preprocess for 16 owned gaussians, scatter sorted ----
    if (tid < 16) {
        int i  = blockIdx.x * 16 + tid;
        int rk = srank[tid];

        float p0 = ld(pos, i*3+0, f32), p1 = ld(pos, i*3+1, f32), p2 = ld(pos, i*3+2, f32);
        float x = R[0]*p0 + R[1]*p1 + R[2]*p2 + T3[0];
        float y = R[3]*p0 + R[4]*p1 + R[5]*p2 + T3[1];
        float z = R[6]*p0 + R[7]*p1 + R[8]*p2 + T3[2];
        float iz = 1.0f / z;
        float u = x * iz, v = y * iz;

        float qw = ld(quat, i*4+0, f32), qx = ld(quat, i*4+1, f32);
        float qy = ld(quat, i*4+2, f32), qz = ld(quat, i*4+3, f32);
        float qn = 1.0f / sqrtf(qw*qw + qx*qx + qy*qy + qz*qz);
        qw *= qn; qx *= qn; qy *= qn; qz *= qn;
        float Rm[3][3];
        Rm[0][0] = 1.0f - 2.0f*(qy*qy + qz*qz);
        Rm[0][1] = 2.0f*(qx*qy - qw*qz);
        Rm[0][2] = 2.0f*(qx*qz + qw*qy);
        Rm[1][0] = 2.0f*(qx*qy + qw*qz);
        Rm[1][1] = 1.0f - 2.0f*(qx*qx + qz*qz);
        Rm[1][2] = 2.0f*(qy*qz - qw*qx);
        Rm[2][0] = 2.0f*(qx*qz - qw*qy);
        Rm[2][1] = 2.0f*(qy*qz + qw*qx);
        Rm[2][2] = 1.0f - 2.0f*(qx*qx + qy*qy);

        float s[3];
        #pragma unroll
        for (int k = 0; k < 3; k++) s[k] = fabsf(ld(scale, i*3+k, f32)) + 1e-4f;

        float RS[3][3];
        #pragma unroll
        for (int a = 0; a < 3; a++)
            #pragma unroll
            for (int b = 0; b < 3; b++) RS[a][b] = Rm[a][b] * s[b];
        float C3[3][3];
        #pragma unroll
        for (int a = 0; a < 3; a++)
            #pragma unroll
            for (int b = 0; b < 3; b++)
                C3[a][b] = RS[a][0]*RS[b][0] + RS[a][1]*RS[b][1] + RS[a][2]*RS[b][2];

        float nx = -x * iz * iz, ny = -y * iz * iz;
        float jw0[3], jw1[3];
        #pragma unroll
        for (int k = 0; k < 3; k++) {
            jw0[k] = iz * R[0*3+k] + nx * R[2*3+k];
            jw1[k] = iz * R[1*3+k] + ny * R[2*3+k];
        }
        float t0[3], t1[3];
        #pragma unroll
        for (int j = 0; j < 3; j++) {
            t0[j] = C3[j][0]*jw0[0] + C3[j][1]*jw0[1] + C3[j][2]*jw0[2];
            t1[j] = C3[j][0]*jw1[0] + C3[j][1]*jw1[1] + C3[j][2]*jw1[2];
        }
        float a = jw0[0]*t0[0] + jw0[1]*t0[1] + jw0[2]*t0[2] + GEPS;
        float b = jw0[0]*t1[0] + jw0[1]*t1[1] + jw0[2]*t1[2];
        float c = jw1[0]*t1[0] + jw1[1]*t1[1] + jw1[2]*t1[2] + GEPS;
        float det  = a*c - b*b;
        float idet = 1.0f / det;
        float Af = -0.5f * LOG2E * (c * idet);
        float Bf = -LOG2E * (-b * idet);
        float Cf = -0.5f * LOG2E * (a * idet);

        float om = (z > NEARZ) ? sigm(ld(opa, i, f32)) : 0.0f;
        float cr = sigm(ld(rgb, i*3+0, f32));
        float cg = sigm(ld(rgb, i*3+1, f32));
        float cb = sigm(ld(rgb, i*3+2, f32));

        // conservative AABB: |d| > 6.5*sqrt(lam_max)  =>  alpha < e^-21
        float mid = 0.5f * (a + c);
        float lam = mid + sqrtf(fmaxf(mid*mid - det, 0.0f));
        float rad = 6.5f * sqrtf(lam) * 128.0f;     // pixels
        float u_px = u * 128.0f + 63.5f;
        float v_px = v * 128.0f + 63.5f;
        unsigned bb = 0xFF00FF00u;                  // "never hits" sentinel
        if (om > 0.0f) {
            int ymn = (int)ceilf (v_px - rad);
            int ymx = (int)floorf(v_px + rad);
            int xmn = (int)ceilf (u_px - rad);
            int xmx = (int)floorf(u_px + rad);
            if (ymx >= 0 && ymn <= 127 && xmx >= 0 && xmn <= 127) {
                ymn = max(ymn, 0); ymx = min(ymx, 127);
                xmn = max(xmn, 0); xmx = min(xmx, 127);
                bb = (unsigned)((ymn << 24) | (ymx << 16) | (xmn << 8) | xmx);
            }
        }

        g_ga_s[rk] = make_float4(u, v, Af, Bf);
        g_gb_s[rk] = make_float4(Cf, om, cr, cg);
        g_cb_s[rk] = cb;
        g_bb_s[rk] = bb;
    }
}

// ---------------------------------------------------------------------------
// Kernel 2: rasterize with ballot culling.
// 256 blocks x 1024 threads. Block = 64-px row strip (row uniform).
// Wave w owns sorted segment w; 64 lanes vector-test 64 AABBs, ballot,
// then walk survivors 4 AT A TIME (R7): the 1-at-a-time ctz walk was a
// serial dependent-load chain (3 uniform L2 loads + waitcnt + ~30cy VALU
// per survivor; no SW pipelining across a data-dependent while loop).
// Batching issues 12 independent loads per latency exposure; ascending ctz
// keeps front-to-back order; tail slots alias survivor 0's (cached) address
// and are masked to alpha=0, so control flow stays wave-uniform.
// ---------------------------------------------------------------------------
__global__ __launch_bounds__(1024)
void raster_kernel(void* __restrict__ out, const void* __restrict__ rot)
{
    __shared__ float4 comb[SEG * 64];

    int tid  = threadIdx.x;
    int lane = tid & 63;
    int w    = __builtin_amdgcn_readfirstlane(tid >> 6);

    int pix = blockIdx.x * 64 + lane;
    int row = blockIdx.x >> 1;          // uniform per block
    int x0  = (blockIdx.x & 1) * 64;    // uniform strip start
    int x1  = x0 + 63;
    int col = x0 + lane;
    float pxf = (col - 63.5f) * (1.0f / 128.0f);
    float pyf = (row - 63.5f) * (1.0f / 128.0f);

    float T = 1.0f, Cr = 0.0f, Cg = 0.0f, Cb = 0.0f;
    int base = w * CHUNK;

    #pragma unroll
    for (int c = 0; c < CHUNK / 64; c++) {          // 2 chunks of 64
        int cbase = base + c * 64;
        unsigned bb = g_bb_s[cbase + lane];          // coalesced vector load
        int ymn =  bb >> 24;
        int ymx = (bb >> 16) & 255;
        int xmn = (bb >>  8) & 255;
        int xmx =  bb        & 255;
        bool hit = (row >= ymn) & (row <= ymx) & (x1 >= xmn) & (x0 <= xmx);
        unsigned long long m = __ballot(hit);
        while (m) {
            // --- peel up to 4 survivors (ascending => depth order kept) ---
            int k0 = __builtin_ctzll(m); m &= m - 1;
            bool v1 = (m != 0ull); int k1 = v1 ? __builtin_ctzll(m) : k0; m &= m - 1;
            bool v2 = (m != 0ull); int k2 = v2 ? __builtin_ctzll(m) : k0; m &= m - 1;
            bool v3 = (m != 0ull); int k3 = v3 ? __builtin_ctzll(m) : k0; m &= m - 1;
            int i0 = cbase + k0, i1 = cbase + k1, i2 = cbase + k2, i3 = cbase + k3;

            // --- 12 independent loads in flight (one latency exposure) ---
            float4 A0 = g_ga_s[i0], A1 = g_ga_s[i1], A2 = g_ga_s[i2], A3 = g_ga_s[i3];
            float4 B0 = g_gb_s[i0], B1 = g_gb_s[i1], B2 = g_gb_s[i2], B3 = g_gb_s[i3];
            float  c0 = g_cb_s[i0], c1 = g_cb_s[i1], c2 = g_cb_s[i2], c3 = g_cb_s[i3];

            // --- 4 alphas in parallel (invalid slots forced to 0) ---
            float dx0 = pxf - A0.x, dy0 = pyf - A0.y;
            float p0  = (A0.z * dx0 + A0.w * dy0) * dx0;
            p0 = fmaf(B0.x * dy0, dy0, p0);
            float al0 = fminf(B0.y * __builtin_amdgcn_exp2f(p0), 0.99f);

            float dx1 = pxf - A1.x, dy1 = pyf - A1.y;
            float p1  = (A1.z * dx1 + A1.w * dy1) * dx1;
            p1 = fmaf(B1.x * dy1, dy1, p1);
            float e1  = v1 ? B1.y : 0.0f;
            float al1 = fminf(e1 * __builtin_amdgcn_exp2f(p1), 0.99f);

            float dx2 = pxf - A2.x, dy2 = pyf - A2.y;
            float p2  = (A2.z * dx2 + A2.w * dy2) * dx2;
            p2 = fmaf(B2.x * dy2, dy2, p2);
            float e2  = v2 ? B2.y : 0.0f;
            float al2 = fminf(e2 * __builtin_amdgcn_exp2f(p2), 0.99f);

            float dx3 = pxf - A3.x, dy3 = pyf - A3.y;
            float p3  = (A3.z * dx3 + A3.w * dy3) * dx3;
            p3 = fmaf(B3.x * dy3, dy3, p3);
            float e3  = v3 ? B3.y : 0.0f;
            float al3 = fminf(e3 * __builtin_amdgcn_exp2f(p3), 0.99f);

            // --- short serial T-chain ---
            float wgt;
            wgt = T * al0; Cr = fmaf(wgt, B0.z, Cr); Cg = fmaf(wgt, B0.w, Cg); Cb = fmaf(wgt, c0, Cb); T -= wgt;
            wgt = T * al1; Cr = fmaf(wgt, B1.z, Cr); Cg = fmaf(wgt, B1.w, Cg); Cb = fmaf(wgt, c1, Cb); T -= wgt;
            wgt = T * al2; Cr = fmaf(wgt, B2.z, Cr); Cg = fmaf(wgt, B2.w, Cg); Cb = fmaf(wgt, c2, Cb); T -= wgt;
            wgt = T * al3; Cr = fmaf(wgt, B3.z, Cr); Cg = fmaf(wgt, B3.w, Cg); Cb = fmaf(wgt, c3, Cb); T -= wgt;
        }
    }

    comb[w * 64 + lane] = make_float4(T, Cr, Cg, Cb);
    __syncthreads();

    if (tid < 64) {
        float Ta = 1.0f, Ra = 0.0f, Ga = 0.0f, Ba = 0.0f;
        #pragma unroll
        for (int s = 0; s < SEG; s++) {
            float4 c4 = comb[s * 64 + lane];
            Ra = fmaf(Ta, c4.y, Ra);
            Ga = fmaf(Ta, c4.z, Ga);
            Ba = fmaf(Ta, c4.w, Ba);
            Ta *= c4.x;
        }
        if (detect_f32(rot)) {
            float* o = (float*)out;
            o[pix*3 + 0] = Ra; o[pix*3 + 1] = Ga; o[pix*3 + 2] = Ba;
        } else {
            __hip_bfloat16* o = (__hip_bfloat16*)out;
            o[pix*3 + 0] = __float2bfloat16(Ra);
            o[pix*3 + 1] = __float2bfloat16(Ga);
            o[pix*3 + 2] = __float2bfloat16(Ba);
        }
    }
}

// ---------------------------------------------------------------------------
extern "C" void kernel_launch(void* const* d_in, const int* in_sizes, int n_in,
                              void* d_out, int out_size, void* d_ws, size_t ws_size,
                              hipStream_t stream)
{
    const void* pos   = d_in[0];
    const void* rgb   = d_in[1];
    const void* opa   = d_in[2];
    const void* quat  = d_in[3];
    const void* scale = d_in[4];
    const void* rot   = d_in[5];
    const void* tran  = d_in[6];

    prep_sort_kernel<<<NG/16, 256, 0, stream>>>(pos, rgb, opa, quat, scale, rot, tran);
    raster_kernel<<<NPIX/64, 1024, 0, stream>>>(d_out, rot);
}